// Round 9
// baseline (96.526 us; speedup 1.0000x reference)
//
#include <hip/hip_runtime.h>
#include <hip/hip_bf16.h>

// Problem: B=N=1024, in_f=1024, OUT_F=32, KD=8
// out[n][0:1024]   = x[n][:]
// M[n][o*8+k]      = sum_f x[n][f] * T[f][o*8+k]        (T flat [1024][256])
// out[n][1024+o]   = sum_{i != n} exp(-sum_k |M[i][o*8+k] - M[n][o*8+k]|)
//
// R8: MEASUREMENT ROUND. Identical to R7 except pairwise repeats its
// compute+store 4x internally (idempotent) so it surfaces in the rocprof
// top-5 with counters, and (T_R8 - T_R7)/3 = single-pass pairwise cost.

#define N_ROWS 1024
#define IN_F   1024
#define OUT_C  1056
#define OK     256   // OUT_F*KD
#define KS     8     // K-split factor
#define KC     128   // K-chunk = IN_F/KS

typedef __attribute__((ext_vector_type(8))) short bf16x8;
typedef __attribute__((ext_vector_type(4))) float f32x4;

__device__ __forceinline__ unsigned short f2bf(float f) {
  unsigned u = __float_as_uint(f);
  u = (u + 0x7FFFu + ((u >> 16) & 1u)) >> 16;   // RNE
  return (unsigned short)u;
}

// ---------------- kernel 1: prep (R7 verbatim) -------------------------------
__global__ __launch_bounds__(256) void prep_kernel(
    const float* __restrict__ x, const float* __restrict__ T,
    float* __restrict__ out, unsigned short* __restrict__ xb,
    unsigned short* __restrict__ Tt) {
  const int b = blockIdx.x, t = threadIdx.x;
  if (b < 512) {
#pragma unroll
    for (int u = 0; u < 2; ++u) {
      int idx = b * 512 + u * 256 + t;          // 262144 float4 groups
      int row = idx >> 8, col4 = idx & 255;     // 256 float4 per row
      float4 v = *reinterpret_cast<const float4*>(x + (size_t)row * IN_F + col4 * 4);
      *reinterpret_cast<float4*>(out + (size_t)row * OUT_C + col4 * 4) = v;
      ushort4 h = make_ushort4(f2bf(v.x), f2bf(v.y), f2bf(v.z), f2bf(v.w));
      *reinterpret_cast<ushort4*>(xb + (size_t)row * IN_F + col4 * 4) = h;
    }
  } else {
    int c = (b - 512) * 4 + (t >> 6);   // 0..255
    int g = t & 63;
#pragma unroll
    for (int u = 0; u < 2; ++u) {
      int k0 = g * 16 + u * 8;
      unsigned short h[8];
#pragma unroll
      for (int j = 0; j < 8; ++j)
        h[j] = f2bf(T[(size_t)(k0 + j) * OK + c]);
      *reinterpret_cast<uint4*>(Tt + (size_t)c * IN_F + k0) =
          *reinterpret_cast<const uint4*>(h);
    }
  }
}

// ---------------- kernel 2: bf16 MFMA GEMM (R7 verbatim) ---------------------
__global__ __launch_bounds__(256) void gemm_mfma_kernel(
    const unsigned short* __restrict__ xb,  // [1024][1024] bf16
    const unsigned short* __restrict__ Tt,  // [256][1024] bf16 (T transposed)
    float* __restrict__ part) {             // [KS][1024][256]
  __shared__ unsigned short asw[64 * 128];
  __shared__ unsigned short bsw[64 * 128];
  const int m0 = blockIdx.x * 64;
  const int n0 = blockIdx.y * 64;
  const int ks = blockIdx.z;
  const int t  = threadIdx.x;

#pragma unroll
  for (int u = 0; u < 4; ++u) {
    int idx = t + 256 * u;
    int row = idx >> 4, slot = idx & 15;
    uint4 va = *reinterpret_cast<const uint4*>(
        xb + (size_t)(m0 + row) * IN_F + ks * KC + slot * 8);
    *reinterpret_cast<uint4*>(asw + row * 128 + ((slot ^ (row & 15)) * 8)) = va;
    uint4 vb = *reinterpret_cast<const uint4*>(
        Tt + (size_t)(n0 + row) * IN_F + ks * KC + slot * 8);
    *reinterpret_cast<uint4*>(bsw + row * 128 + ((slot ^ (row & 15)) * 8)) = vb;
  }
  __syncthreads();

  const int l  = t & 63, w = t >> 6;
  const int lr = l & 15, lg = l >> 4;
  f32x4 acc0 = {0.f, 0.f, 0.f, 0.f};
  f32x4 acc1 = {0.f, 0.f, 0.f, 0.f};
  f32x4 acc2 = {0.f, 0.f, 0.f, 0.f};
  f32x4 acc3 = {0.f, 0.f, 0.f, 0.f};

  const int arow = w * 16 + lr;
  const int aswz = arow & 15;
#pragma unroll
  for (int kk = 0; kk < 4; ++kk) {
    int slotA = kk * 4 + lg;
    bf16x8 a = *reinterpret_cast<const bf16x8*>(
        asw + arow * 128 + ((slotA ^ aswz) * 8));
    int sb = (slotA ^ lr) * 8;
    bf16x8 b0 = *reinterpret_cast<const bf16x8*>(bsw + (lr)      * 128 + sb);
    bf16x8 b1 = *reinterpret_cast<const bf16x8*>(bsw + (16 + lr) * 128 + sb);
    bf16x8 b2 = *reinterpret_cast<const bf16x8*>(bsw + (32 + lr) * 128 + sb);
    bf16x8 b3 = *reinterpret_cast<const bf16x8*>(bsw + (48 + lr) * 128 + sb);
    acc0 = __builtin_amdgcn_mfma_f32_16x16x32_bf16(a, b0, acc0, 0, 0, 0);
    acc1 = __builtin_amdgcn_mfma_f32_16x16x32_bf16(a, b1, acc1, 0, 0, 0);
    acc2 = __builtin_amdgcn_mfma_f32_16x16x32_bf16(a, b2, acc2, 0, 0, 0);
    acc3 = __builtin_amdgcn_mfma_f32_16x16x32_bf16(a, b3, acc3, 0, 0, 0);
  }

  float* dst = part + (size_t)ks * (N_ROWS * OK)
             + (size_t)(m0 + w * 16 + lg * 4) * OK + n0 + lr;
#pragma unroll
  for (int r = 0; r < 4; ++r) {
    dst[(size_t)r * OK]      = acc0[r];
    dst[(size_t)r * OK + 16] = acc1[r];
    dst[(size_t)r * OK + 32] = acc2[r];
    dst[(size_t)r * OK + 48] = acc3[r];
  }
}

// ---------------- kernel 3: reduce K-split partials (R7 verbatim) ------------
__global__ __launch_bounds__(256) void reduce_kernel(
    const float* __restrict__ part, float* __restrict__ M) {
  int g = blockIdx.x * 256 + threadIdx.x;
  const float4* p = reinterpret_cast<const float4*>(part);
  float4 s = p[g];
#pragma unroll
  for (int sl = 1; sl < KS; ++sl) {
    float4 v = p[g + (size_t)sl * (N_ROWS * OK / 4)];
    s.x += v.x; s.y += v.y; s.z += v.z; s.w += v.w;
  }
  reinterpret_cast<float4*>(M)[g] = s;
}

// ---------------- fallback GEMM (small ws): single-pass fp32 -----------------
#define BK 16
__global__ __launch_bounds__(256) void gemm32_kernel(
    const float* __restrict__ A, const float* __restrict__ Bm, float* __restrict__ M) {
  __shared__ float as2[BK][32];
  __shared__ float bs2[BK][32];
  int m0 = blockIdx.x * 32;
  int n0 = blockIdx.y * 32;
  int t  = threadIdx.x;
  int ty = t >> 4, tx = t & 15;
  float c00 = 0.f, c01 = 0.f, c10 = 0.f, c11 = 0.f;
  for (int k0 = 0; k0 < IN_F; k0 += BK) {
    if (t < 128) {
      int row = t >> 2, q = t & 3;
      float4 v = *reinterpret_cast<const float4*>(A + (size_t)(m0 + row) * IN_F + k0 + q * 4);
      as2[q * 4 + 0][row] = v.x; as2[q * 4 + 1][row] = v.y;
      as2[q * 4 + 2][row] = v.z; as2[q * 4 + 3][row] = v.w;
    } else {
      int tt = t - 128;
      int row = tt >> 3, q = tt & 7;
      float4 v = *reinterpret_cast<const float4*>(Bm + (size_t)(k0 + row) * OK + n0 + q * 4);
      *reinterpret_cast<float4*>(&bs2[row][q * 4]) = v;
    }
    __syncthreads();
#pragma unroll
    for (int kk = 0; kk < BK; ++kk) {
      float2 a = *reinterpret_cast<const float2*>(&as2[kk][ty * 2]);
      float2 b = *reinterpret_cast<const float2*>(&bs2[kk][tx * 2]);
      c00 += a.x * b.x; c01 += a.x * b.y;
      c10 += a.y * b.x; c11 += a.y * b.y;
    }
    __syncthreads();
  }
  int r = m0 + ty * 2, c = n0 + tx * 2;
  M[(size_t)r * OK + c]           = c00;
  M[(size_t)r * OK + c + 1]       = c01;
  M[(size_t)(r + 1) * OK + c]     = c10;
  M[(size_t)(r + 1) * OK + c + 1] = c11;
}

// ---------------- kernel 4: pairwise v2, 4x INTERNAL REPEAT (measurement) ----
// Stage once; recompute + re-store the identical result 4 times. Idempotent:
// output bit-identical to single pass. asm identity on acc defeats LICM so
// each rep truly re-executes the i-loop (guide rule #17).
__global__ __launch_bounds__(256) void pairwise_kernel(
    const float* __restrict__ M, float* __restrict__ out) {
  __shared__ float sm[N_ROWS][8];   // 32 KB: M[:, o, :]
  __shared__ float red[4][64];

  int o  = blockIdx.x;
  int jt = blockIdx.y;
  int t  = threadIdx.x;

#pragma unroll
  for (int idx = t; idx < 2048; idx += 256) {
    int row = idx >> 1, half = idx & 1;
    *reinterpret_cast<float4*>(&sm[row][half * 4]) =
        *reinterpret_cast<const float4*>(M + (size_t)row * OK + o * 8 + half * 4);
  }
  __syncthreads();

  int jl = t & 63, s = t >> 6;
  int j  = jt * 64 + jl;

  float4 ra = *reinterpret_cast<const float4*>(&sm[j][0]);
  float4 rb = *reinterpret_cast<const float4*>(&sm[j][4]);

  for (int rep = 0; rep < 4; ++rep) {
    float acc = 0.f;
    asm volatile("" : "+v"(acc));   // opaque init: i-loop not loop-invariant
    int i0 = s * 256;
    for (int i = i0; i < i0 + 256; ++i) {
      float4 va = *reinterpret_cast<const float4*>(&sm[i][0]);
      float4 vb = *reinterpret_cast<const float4*>(&sm[i][4]);
      float d = fabsf(va.x - ra.x) + fabsf(va.y - ra.y) +
                fabsf(va.z - ra.z) + fabsf(va.w - ra.w) +
                fabsf(vb.x - rb.x) + fabsf(vb.y - rb.y) +
                fabsf(vb.z - rb.z) + fabsf(vb.w - rb.w);
      if (d < 30.f) acc += __expf(-d);
    }
    if ((j >> 8) == s) acc -= 1.0f;   // exact self term exp(0)=1

    red[s][jl] = acc;
    __syncthreads();

    if (t < 64) {
      float v = red[0][t] + red[1][t] + red[2][t] + red[3][t];
      int jj = jt * 64 + t;
      out[(size_t)jj * OUT_C + 1024 + o] = v;   // same value every rep
    }
    __syncthreads();
  }
}

// fallback copy (only used on fallback path)
__global__ __launch_bounds__(256) void copy_x_kernel(
    const float* __restrict__ x, float* __restrict__ out) {
  int n = blockIdx.x;
  int c = threadIdx.x * 4;
  float4 v = *reinterpret_cast<const float4*>(x + (size_t)n * IN_F + c);
  *reinterpret_cast<float4*>(out + (size_t)n * OUT_C + c) = v;
}

extern "C" void kernel_launch(void* const* d_in, const int* in_sizes, int n_in,
                              void* d_out, int out_size, void* d_ws, size_t ws_size,
                              hipStream_t stream) {
  const float* x = (const float*)d_in[0];   // [1024][1024]
  const float* T = (const float*)d_in[1];   // [1024][256]
  float* out = (float*)d_out;               // [1024][1056]

  const size_t mElems = (size_t)N_ROWS * OK;           // 262144
  const size_t needed = KS * mElems * 4                // part  8 MB
                      + mElems * 4                     // M     1 MB
                      + (size_t)N_ROWS * IN_F * 2      // xb    2 MB
                      + (size_t)OK * IN_F * 2;         // Tt  0.5 MB

  if (ws_size >= needed) {
    float* part = (float*)d_ws;
    float* M    = part + KS * mElems;
    unsigned short* xb = (unsigned short*)(M + mElems);
    unsigned short* Tt = xb + (size_t)N_ROWS * IN_F;

    prep_kernel<<<dim3(576), dim3(256), 0, stream>>>(x, T, out, xb, Tt);
    gemm_mfma_kernel<<<dim3(16, 4, KS), dim3(256), 0, stream>>>(xb, Tt, part);
    reduce_kernel<<<dim3(256), dim3(256), 0, stream>>>(part, M);
    pairwise_kernel<<<dim3(32, 16), dim3(256), 0, stream>>>(M, out);
  } else {
    float* M = (float*)d_ws;
    copy_x_kernel<<<dim3(N_ROWS), dim3(256), 0, stream>>>(x, out);
    gemm32_kernel<<<dim3(32, 8), dim3(256), 0, stream>>>(x, T, M);
    pairwise_kernel<<<dim3(32, 16), dim3(256), 0, stream>>>(M, out);
  }
}

// Round 10
// 42.159 us; speedup vs baseline: 2.2896x; 2.2896x over previous
//
#include <hip/hip_runtime.h>
#include <hip/hip_bf16.h>

// Problem: B=N=1024, in_f=1024, OUT_F=32, KD=8
// out[n][0:1024]   = x[n][:]
// M[n][o*8+k]      = sum_f x[n][f] * T[f][o*8+k]        (T flat [1024][256])
// out[n][1024+o]   = sum_{i != n} exp(-sum_k |M[i][o*8+k] - M[n][o*8+k]|)
//
// R9: pairwise v7 = v2 skeleton, BRANCHLESS (unconditional exp underflow) +
// unroll 4 + hoisted LDS base. All other kernels R7-verbatim.

#define N_ROWS 1024
#define IN_F   1024
#define OUT_C  1056
#define OK     256   // OUT_F*KD
#define KS     8     // K-split factor
#define KC     128   // K-chunk = IN_F/KS

typedef __attribute__((ext_vector_type(8))) short bf16x8;
typedef __attribute__((ext_vector_type(4))) float f32x4;

__device__ __forceinline__ unsigned short f2bf(float f) {
  unsigned u = __float_as_uint(f);
  u = (u + 0x7FFFu + ((u >> 16) & 1u)) >> 16;   // RNE
  return (unsigned short)u;
}

// ---------------- kernel 1: prep (R7 verbatim) -------------------------------
__global__ __launch_bounds__(256) void prep_kernel(
    const float* __restrict__ x, const float* __restrict__ T,
    float* __restrict__ out, unsigned short* __restrict__ xb,
    unsigned short* __restrict__ Tt) {
  const int b = blockIdx.x, t = threadIdx.x;
  if (b < 512) {
#pragma unroll
    for (int u = 0; u < 2; ++u) {
      int idx = b * 512 + u * 256 + t;          // 262144 float4 groups
      int row = idx >> 8, col4 = idx & 255;     // 256 float4 per row
      float4 v = *reinterpret_cast<const float4*>(x + (size_t)row * IN_F + col4 * 4);
      *reinterpret_cast<float4*>(out + (size_t)row * OUT_C + col4 * 4) = v;
      ushort4 h = make_ushort4(f2bf(v.x), f2bf(v.y), f2bf(v.z), f2bf(v.w));
      *reinterpret_cast<ushort4*>(xb + (size_t)row * IN_F + col4 * 4) = h;
    }
  } else {
    int c = (b - 512) * 4 + (t >> 6);   // 0..255
    int g = t & 63;
#pragma unroll
    for (int u = 0; u < 2; ++u) {
      int k0 = g * 16 + u * 8;
      unsigned short h[8];
#pragma unroll
      for (int j = 0; j < 8; ++j)
        h[j] = f2bf(T[(size_t)(k0 + j) * OK + c]);
      *reinterpret_cast<uint4*>(Tt + (size_t)c * IN_F + k0) =
          *reinterpret_cast<const uint4*>(h);
    }
  }
}

// ---------------- kernel 2: bf16 MFMA GEMM (R7 verbatim) ---------------------
__global__ __launch_bounds__(256) void gemm_mfma_kernel(
    const unsigned short* __restrict__ xb,  // [1024][1024] bf16
    const unsigned short* __restrict__ Tt,  // [256][1024] bf16 (T transposed)
    float* __restrict__ part) {             // [KS][1024][256]
  __shared__ unsigned short asw[64 * 128];
  __shared__ unsigned short bsw[64 * 128];
  const int m0 = blockIdx.x * 64;
  const int n0 = blockIdx.y * 64;
  const int ks = blockIdx.z;
  const int t  = threadIdx.x;

#pragma unroll
  for (int u = 0; u < 4; ++u) {
    int idx = t + 256 * u;
    int row = idx >> 4, slot = idx & 15;
    uint4 va = *reinterpret_cast<const uint4*>(
        xb + (size_t)(m0 + row) * IN_F + ks * KC + slot * 8);
    *reinterpret_cast<uint4*>(asw + row * 128 + ((slot ^ (row & 15)) * 8)) = va;
    uint4 vb = *reinterpret_cast<const uint4*>(
        Tt + (size_t)(n0 + row) * IN_F + ks * KC + slot * 8);
    *reinterpret_cast<uint4*>(bsw + row * 128 + ((slot ^ (row & 15)) * 8)) = vb;
  }
  __syncthreads();

  const int l  = t & 63, w = t >> 6;
  const int lr = l & 15, lg = l >> 4;
  f32x4 acc0 = {0.f, 0.f, 0.f, 0.f};
  f32x4 acc1 = {0.f, 0.f, 0.f, 0.f};
  f32x4 acc2 = {0.f, 0.f, 0.f, 0.f};
  f32x4 acc3 = {0.f, 0.f, 0.f, 0.f};

  const int arow = w * 16 + lr;
  const int aswz = arow & 15;
#pragma unroll
  for (int kk = 0; kk < 4; ++kk) {
    int slotA = kk * 4 + lg;
    bf16x8 a = *reinterpret_cast<const bf16x8*>(
        asw + arow * 128 + ((slotA ^ aswz) * 8));
    int sb = (slotA ^ lr) * 8;
    bf16x8 b0 = *reinterpret_cast<const bf16x8*>(bsw + (lr)      * 128 + sb);
    bf16x8 b1 = *reinterpret_cast<const bf16x8*>(bsw + (16 + lr) * 128 + sb);
    bf16x8 b2 = *reinterpret_cast<const bf16x8*>(bsw + (32 + lr) * 128 + sb);
    bf16x8 b3 = *reinterpret_cast<const bf16x8*>(bsw + (48 + lr) * 128 + sb);
    acc0 = __builtin_amdgcn_mfma_f32_16x16x32_bf16(a, b0, acc0, 0, 0, 0);
    acc1 = __builtin_amdgcn_mfma_f32_16x16x32_bf16(a, b1, acc1, 0, 0, 0);
    acc2 = __builtin_amdgcn_mfma_f32_16x16x32_bf16(a, b2, acc2, 0, 0, 0);
    acc3 = __builtin_amdgcn_mfma_f32_16x16x32_bf16(a, b3, acc3, 0, 0, 0);
  }

  float* dst = part + (size_t)ks * (N_ROWS * OK)
             + (size_t)(m0 + w * 16 + lg * 4) * OK + n0 + lr;
#pragma unroll
  for (int r = 0; r < 4; ++r) {
    dst[(size_t)r * OK]      = acc0[r];
    dst[(size_t)r * OK + 16] = acc1[r];
    dst[(size_t)r * OK + 32] = acc2[r];
    dst[(size_t)r * OK + 48] = acc3[r];
  }
}

// ---------------- kernel 3: reduce K-split partials (R7 verbatim) ------------
__global__ __launch_bounds__(256) void reduce_kernel(
    const float* __restrict__ part, float* __restrict__ M) {
  int g = blockIdx.x * 256 + threadIdx.x;
  const float4* p = reinterpret_cast<const float4*>(part);
  float4 s = p[g];
#pragma unroll
  for (int sl = 1; sl < KS; ++sl) {
    float4 v = p[g + (size_t)sl * (N_ROWS * OK / 4)];
    s.x += v.x; s.y += v.y; s.z += v.z; s.w += v.w;
  }
  reinterpret_cast<float4*>(M)[g] = s;
}

// ---------------- fallback GEMM (small ws): single-pass fp32 -----------------
#define BK 16
__global__ __launch_bounds__(256) void gemm32_kernel(
    const float* __restrict__ A, const float* __restrict__ Bm, float* __restrict__ M) {
  __shared__ float as2[BK][32];
  __shared__ float bs2[BK][32];
  int m0 = blockIdx.x * 32;
  int n0 = blockIdx.y * 32;
  int t  = threadIdx.x;
  int ty = t >> 4, tx = t & 15;
  float c00 = 0.f, c01 = 0.f, c10 = 0.f, c11 = 0.f;
  for (int k0 = 0; k0 < IN_F; k0 += BK) {
    if (t < 128) {
      int row = t >> 2, q = t & 3;
      float4 v = *reinterpret_cast<const float4*>(A + (size_t)(m0 + row) * IN_F + k0 + q * 4);
      as2[q * 4 + 0][row] = v.x; as2[q * 4 + 1][row] = v.y;
      as2[q * 4 + 2][row] = v.z; as2[q * 4 + 3][row] = v.w;
    } else {
      int tt = t - 128;
      int row = tt >> 3, q = tt & 7;
      float4 v = *reinterpret_cast<const float4*>(Bm + (size_t)(k0 + row) * OK + n0 + q * 4);
      *reinterpret_cast<float4*>(&bs2[row][q * 4]) = v;
    }
    __syncthreads();
#pragma unroll
    for (int kk = 0; kk < BK; ++kk) {
      float2 a = *reinterpret_cast<const float2*>(&as2[kk][ty * 2]);
      float2 b = *reinterpret_cast<const float2*>(&bs2[kk][tx * 2]);
      c00 += a.x * b.x; c01 += a.x * b.y;
      c10 += a.y * b.x; c11 += a.y * b.y;
    }
    __syncthreads();
  }
  int r = m0 + ty * 2, c = n0 + tx * 2;
  M[(size_t)r * OK + c]           = c00;
  M[(size_t)r * OK + c + 1]       = c01;
  M[(size_t)(r + 1) * OK + c]     = c10;
  M[(size_t)(r + 1) * OK + c + 1] = c11;
}

// ---------------- kernel 4: pairwise exp(-L1) v7 -----------------------------
// v2 skeleton: grid (o:32, jt:16) = 512 blocks x 256 thr, stage all 1024 rows.
// CHANGES vs v2: branchless accumulate (exp underflows for large d; no exec-
// mask churn) + unroll 4 + hoisted LDS base pointer (immediate-offset b128s).
__global__ __launch_bounds__(256) void pairwise_kernel(
    const float* __restrict__ M, float* __restrict__ out) {
  __shared__ float sm[N_ROWS][8];   // 32 KB: M[:, o, :]
  __shared__ float red[4][64];

  int o  = blockIdx.x;
  int jt = blockIdx.y;
  int t  = threadIdx.x;

#pragma unroll
  for (int idx = t; idx < 2048; idx += 256) {
    int row = idx >> 1, half = idx & 1;
    *reinterpret_cast<float4*>(&sm[row][half * 4]) =
        *reinterpret_cast<const float4*>(M + (size_t)row * OK + o * 8 + half * 4);
  }
  __syncthreads();

  int jl = t & 63, s = t >> 6;
  int j  = jt * 64 + jl;

  float4 ra = *reinterpret_cast<const float4*>(&sm[j][0]);
  float4 rb = *reinterpret_cast<const float4*>(&sm[j][4]);

  float acc = 0.f;
  const float* base = &sm[s * 256][0];   // wave's 256-row LDS window
#pragma unroll 4
  for (int i = 0; i < 256; ++i) {
    float4 va = *reinterpret_cast<const float4*>(base + i * 8);
    float4 vb = *reinterpret_cast<const float4*>(base + i * 8 + 4);
    float d = fabsf(va.x - ra.x) + fabsf(va.y - ra.y) +
              fabsf(va.z - ra.z) + fabsf(va.w - ra.w) +
              fabsf(vb.x - rb.x) + fabsf(vb.y - rb.y) +
              fabsf(vb.z - rb.z) + fabsf(vb.w - rb.w);
    acc += __expf(-d);   // d large -> underflow to 0; no branch, no divergence
  }
  if ((j >> 8) == s) acc -= 1.0f;   // exact self term exp(0)=1

  red[s][jl] = acc;
  __syncthreads();

  if (t < 64) {
    float v = red[0][t] + red[1][t] + red[2][t] + red[3][t];
    int jj = jt * 64 + t;
    out[(size_t)jj * OUT_C + 1024 + o] = v;
  }
}

// fallback copy (only used on fallback path)
__global__ __launch_bounds__(256) void copy_x_kernel(
    const float* __restrict__ x, float* __restrict__ out) {
  int n = blockIdx.x;
  int c = threadIdx.x * 4;
  float4 v = *reinterpret_cast<const float4*>(x + (size_t)n * IN_F + c);
  *reinterpret_cast<float4*>(out + (size_t)n * OUT_C + c) = v;
}

extern "C" void kernel_launch(void* const* d_in, const int* in_sizes, int n_in,
                              void* d_out, int out_size, void* d_ws, size_t ws_size,
                              hipStream_t stream) {
  const float* x = (const float*)d_in[0];   // [1024][1024]
  const float* T = (const float*)d_in[1];   // [1024][256]
  float* out = (float*)d_out;               // [1024][1056]

  const size_t mElems = (size_t)N_ROWS * OK;           // 262144
  const size_t needed = KS * mElems * 4                // part  8 MB
                      + mElems * 4                     // M     1 MB
                      + (size_t)N_ROWS * IN_F * 2      // xb    2 MB
                      + (size_t)OK * IN_F * 2;         // Tt  0.5 MB

  if (ws_size >= needed) {
    float* part = (float*)d_ws;
    float* M    = part + KS * mElems;
    unsigned short* xb = (unsigned short*)(M + mElems);
    unsigned short* Tt = xb + (size_t)N_ROWS * IN_F;

    prep_kernel<<<dim3(576), dim3(256), 0, stream>>>(x, T, out, xb, Tt);
    gemm_mfma_kernel<<<dim3(16, 4, KS), dim3(256), 0, stream>>>(xb, Tt, part);
    reduce_kernel<<<dim3(256), dim3(256), 0, stream>>>(part, M);
    pairwise_kernel<<<dim3(32, 16), dim3(256), 0, stream>>>(M, out);
  } else {
    float* M = (float*)d_ws;
    copy_x_kernel<<<dim3(N_ROWS), dim3(256), 0, stream>>>(x, out);
    gemm32_kernel<<<dim3(32, 8), dim3(256), 0, stream>>>(x, T, M);
    pairwise_kernel<<<dim3(32, 16), dim3(256), 0, stream>>>(M, out);
  }
}